// Round 1
// baseline (214.572 us; speedup 1.0000x reference)
//
#include <hip/hip_runtime.h>
#include <hip/hip_bf16.h>

#define NN 8192
#define DD 256

typedef __attribute__((ext_vector_type(8))) short short8;
typedef __attribute__((ext_vector_type(4))) float f32x4;

// round-to-nearest-even fp32 -> bf16 (no NaN inputs here)
__device__ __forceinline__ unsigned short f2bf(float x) {
    unsigned int u = __float_as_uint(x);
    u += 0x7fff + ((u >> 16) & 1);
    return (unsigned short)(u >> 16);
}

// One wave per row: L2-normalize both features, fold logit_scale into f1,
// emit bf16 rows + exact fp32 diagonal diag[i] = s * <f1n_i, f2n_i>.
__global__ __launch_bounds__(256) void nrm_kernel(
    const float* __restrict__ f1, const float* __restrict__ f2,
    const float* __restrict__ scale_p,
    unsigned short* __restrict__ f1n, unsigned short* __restrict__ f2n,
    float* __restrict__ diag)
{
    const int w = threadIdx.x >> 6, lane = threadIdx.x & 63;
    const int row = blockIdx.x * 4 + w;
    const float4 a = reinterpret_cast<const float4*>(f1 + (size_t)row * DD)[lane];
    const float4 b = reinterpret_cast<const float4*>(f2 + (size_t)row * DD)[lane];
    float sa = a.x * a.x + a.y * a.y + a.z * a.z + a.w * a.w;
    float sb = b.x * b.x + b.y * b.y + b.z * b.z + b.w * b.w;
    float sab = a.x * b.x + a.y * b.y + a.z * b.z + a.w * b.w;
#pragma unroll
    for (int off = 1; off < 64; off <<= 1) {
        sa += __shfl_xor(sa, off);
        sb += __shfl_xor(sb, off);
        sab += __shfl_xor(sab, off);
    }
    const float s = scale_p[0];
    const float n1 = fmaxf(sqrtf(sa), 1e-12f);
    const float n2 = fmaxf(sqrtf(sb), 1e-12f);
    if (lane == 0) diag[row] = s * sab / (n1 * n2);
    const float r1 = s / n1, r2 = 1.0f / n2;
    ushort4 o1, o2;
    o1.x = f2bf(a.x * r1); o1.y = f2bf(a.y * r1);
    o1.z = f2bf(a.z * r1); o1.w = f2bf(a.w * r1);
    o2.x = f2bf(b.x * r2); o2.y = f2bf(b.y * r2);
    o2.z = f2bf(b.z * r2); o2.w = f2bf(b.w * r2);
    reinterpret_cast<ushort4*>(f1n + (size_t)row * DD)[lane] = o1;
    reinterpret_cast<ushort4*>(f2n + (size_t)row * DD)[lane] = o2;
}

// 128x128 tile of sim = (scaled f1n) @ f2n^T, full K=256 in LDS.
// LDS layout XOR-swizzled per 16B chunk: slot(r, c) holds global chunk c^(r&7).
// global_load_lds writes linearly, so the *source* address is pre-swizzled.
__global__ __launch_bounds__(256, 1) void gemm_kernel(
    const unsigned short* __restrict__ f1n, const unsigned short* __restrict__ f2n,
    float* __restrict__ rowsum, float* __restrict__ rowsumexp,
    float* __restrict__ colsum, float* __restrict__ colsumexp)
{
    __shared__ char lds[131072];
    char* As = lds;
    char* Bs = lds + 65536;
    const int bid = blockIdx.x;
    const int bm = bid >> 6, bn = bid & 63;
    const int w = threadIdx.x >> 6, lane = threadIdx.x & 63;

    const char* srcA = (const char*)f1n + (size_t)bm * 128 * 512;
    const char* srcB = (const char*)f2n + (size_t)bn * 128 * 512;
#pragma unroll
    for (int i = 0; i < 16; ++i) {
        const int rloc = w * 32 + i * 2 + (lane >> 5);      // row in tile this lane feeds
        const int chunk = (lane & 31) ^ (rloc & 7);          // pre-swizzled source chunk
        const int goff = rloc * 512 + chunk * 16;
        char* dA = As + (w * 32 + i * 2) * 512;              // wave-uniform LDS base
        char* dB = Bs + (w * 32 + i * 2) * 512;
        __builtin_amdgcn_global_load_lds(
            (const __attribute__((address_space(1))) unsigned int*)(srcA + goff),
            (__attribute__((address_space(3))) unsigned int*)dA, 16, 0, 0);
        __builtin_amdgcn_global_load_lds(
            (const __attribute__((address_space(1))) unsigned int*)(srcB + goff),
            (__attribute__((address_space(3))) unsigned int*)dB, 16, 0, 0);
    }
    __syncthreads();

    f32x4 acc[4][4];
#pragma unroll
    for (int m = 0; m < 4; ++m)
#pragma unroll
        for (int n = 0; n < 4; ++n)
            acc[m][n] = (f32x4){0.f, 0.f, 0.f, 0.f};

    const int wr = (w >> 1) * 64, wc = (w & 1) * 64;   // 2x2 wave grid, 64x64 each
    const int lhi = lane >> 4, llo = lane & 15;

#pragma unroll
    for (int k = 0; k < 8; ++k) {
        short8 av[4], bv[4];
        const int kb = k * 64 + lhi * 16;              // byte offset of this lane's 8 bf16
#pragma unroll
        for (int m = 0; m < 4; ++m) {
            const int ra = wr + m * 16 + llo;
            av[m] = *(const short8*)(As + ra * 512 + (kb ^ ((ra & 7) << 4)));
            const int rb = wc + m * 16 + llo;
            bv[m] = *(const short8*)(Bs + rb * 512 + (kb ^ ((rb & 7) << 4)));
        }
#pragma unroll
        for (int m = 0; m < 4; ++m)
#pragma unroll
            for (int n = 0; n < 4; ++n)
                acc[m][n] = __builtin_amdgcn_mfma_f32_16x16x32_bf16(av[m], bv[n], acc[m][n], 0, 0, 0);
    }

    // Epilogue: C/D layout col=lane&15, row=(lane>>4)*4+j (m89-verified).
    const int grow = bm * 128 + wr + lhi * 4;
    const int gcol = bn * 128 + wc + llo;
    float cvv[4] = {0.f, 0.f, 0.f, 0.f}, cee[4] = {0.f, 0.f, 0.f, 0.f};
#pragma unroll
    for (int m = 0; m < 4; ++m) {
#pragma unroll
        for (int j = 0; j < 4; ++j) {
            float rv = 0.f, re = 0.f;
#pragma unroll
            for (int n = 0; n < 4; ++n) {
                const float x = acc[m][n][j];
                const float ex = __expf(x);
                rv += x; re += ex;
                cvv[n] += x; cee[n] += ex;
            }
#pragma unroll
            for (int off = 1; off < 16; off <<= 1) {   // reduce across the 16 cols
                rv += __shfl_xor(rv, off);
                re += __shfl_xor(re, off);
            }
            if (llo == 0) {
                const int r = grow + m * 16 + j;
                atomicAdd(&rowsum[r], rv);
                atomicAdd(&rowsumexp[r], re);
            }
        }
    }
#pragma unroll
    for (int n = 0; n < 4; ++n) {                      // reduce across the 16 rows
        float v = cvv[n], e = cee[n];
        v += __shfl_xor(v, 16); e += __shfl_xor(e, 16);
        v += __shfl_xor(v, 32); e += __shfl_xor(e, 32);
        if (lhi == 0) {
            const int c = gcol + n * 16;
            atomicAdd(&colsum[c], v);
            atomicAdd(&colsumexp[c], e);
        }
    }
}

__global__ __launch_bounds__(256) void fin_kernel(
    const float* __restrict__ rowsum, const float* __restrict__ rowsumexp,
    const float* __restrict__ colsum, const float* __restrict__ colsumexp,
    const float* __restrict__ diag, const float* __restrict__ wts,
    float* __restrict__ out)
{
    const float invN = 1.0f / (float)NN;
    float accum = 0.f;
    for (int i = threadIdx.x; i < NN; i += 256) {
        const float eps = 1.f - 0.9f / (1.f + __expf(-5.f * wts[i]));
        const float om = 1.f - eps;
        const float d = diag[i];
        accum += __logf(rowsumexp[i]) - om * d - eps * rowsum[i] * invN;
        accum += __logf(colsumexp[i]) - om * d - eps * colsum[i] * invN;
    }
#pragma unroll
    for (int off = 1; off < 64; off <<= 1) accum += __shfl_xor(accum, off);
    __shared__ float red[4];
    if ((threadIdx.x & 63) == 0) red[threadIdx.x >> 6] = accum;
    __syncthreads();
    if (threadIdx.x == 0)
        out[0] = (red[0] + red[1] + red[2] + red[3]) * (invN * 0.5f);
}

extern "C" void kernel_launch(void* const* d_in, const int* in_sizes, int n_in,
                              void* d_out, int out_size, void* d_ws, size_t ws_size,
                              hipStream_t stream) {
    (void)in_sizes; (void)n_in; (void)out_size; (void)ws_size;
    const float* f1 = (const float*)d_in[0];
    const float* f2 = (const float*)d_in[1];
    const float* scale = (const float*)d_in[2];
    const float* wts = (const float*)d_in[3];
    float* out = (float*)d_out;

    char* ws = (char*)d_ws;
    unsigned short* f1n = (unsigned short*)ws;                              // 4 MB
    unsigned short* f2n = (unsigned short*)(ws + (size_t)4 * 1024 * 1024);  // 4 MB
    float* acc = (float*)(ws + (size_t)8 * 1024 * 1024);
    float* rowsum = acc;
    float* rowsumexp = acc + NN;
    float* colsum = acc + 2 * NN;
    float* colsumexp = acc + 3 * NN;
    float* diag = acc + 4 * NN;

    hipMemsetAsync(acc, 0, (size_t)4 * NN * sizeof(float), stream);
    nrm_kernel<<<NN / 4, 256, 0, stream>>>(f1, f2, scale, f1n, f2n, diag);
    gemm_kernel<<<64 * 64, 256, 0, stream>>>(f1n, f2n, rowsum, rowsumexp, colsum, colsumexp);
    fin_kernel<<<1, 256, 0, stream>>>(rowsum, rowsumexp, colsum, colsumexp, diag, wts, out);
}

// Round 2
// 184.462 us; speedup vs baseline: 1.1632x; 1.1632x over previous
//
#include <hip/hip_runtime.h>
#include <hip/hip_bf16.h>

#define NN 8192
#define DD 256

typedef __attribute__((ext_vector_type(8))) short short8;
typedef __attribute__((ext_vector_type(4))) float f32x4;

__device__ __forceinline__ unsigned short f2bf(float x) {
    unsigned int u = __float_as_uint(x);
    u += 0x7fff + ((u >> 16) & 1);
    return (unsigned short)(u >> 16);
}

// One wave per row: L2-normalize both features, fold logit_scale into f1,
// emit bf16 rows + exact fp32 diagonal diag[i] = s * <f1n_i, f2n_i>.
__global__ __launch_bounds__(256) void nrm_kernel(
    const float* __restrict__ f1, const float* __restrict__ f2,
    const float* __restrict__ scale_p,
    unsigned short* __restrict__ f1n, unsigned short* __restrict__ f2n,
    float* __restrict__ diag)
{
    const int w = threadIdx.x >> 6, lane = threadIdx.x & 63;
    const int row = blockIdx.x * 4 + w;
    const float4 a = reinterpret_cast<const float4*>(f1 + (size_t)row * DD)[lane];
    const float4 b = reinterpret_cast<const float4*>(f2 + (size_t)row * DD)[lane];
    float sa = a.x * a.x + a.y * a.y + a.z * a.z + a.w * a.w;
    float sb = b.x * b.x + b.y * b.y + b.z * b.z + b.w * b.w;
    float sab = a.x * b.x + a.y * b.y + a.z * b.z + a.w * b.w;
#pragma unroll
    for (int off = 1; off < 64; off <<= 1) {
        sa += __shfl_xor(sa, off);
        sb += __shfl_xor(sb, off);
        sab += __shfl_xor(sab, off);
    }
    const float s = scale_p[0];
    const float n1 = fmaxf(sqrtf(sa), 1e-12f);
    const float n2 = fmaxf(sqrtf(sb), 1e-12f);
    if (lane == 0) diag[row] = s * sab / (n1 * n2);
    const float r1 = s / n1, r2 = 1.0f / n2;
    ushort4 o1, o2;
    o1.x = f2bf(a.x * r1); o1.y = f2bf(a.y * r1);
    o1.z = f2bf(a.z * r1); o1.w = f2bf(a.w * r1);
    o2.x = f2bf(b.x * r2); o2.y = f2bf(b.y * r2);
    o2.z = f2bf(b.z * r2); o2.w = f2bf(b.w * r2);
    reinterpret_cast<ushort4*>(f1n + (size_t)row * DD)[lane] = o1;
    reinterpret_cast<ushort4*>(f2n + (size_t)row * DD)[lane] = o2;
}

// m97-structure GEMM: 128x128 tile, BK=64 K-loop, 32KB LDS (~3 blocks/CU).
// LDS rows are 128B (64 bf16); 16B chunks XOR-swizzled: LDS[r][c] = G[r][c^(r&7)].
// global_load_lds writes linearly (base + lane*16), so the SOURCE chunk is
// pre-swizzled; ds_read applies the same XOR (rule #21: both sides).
__global__ __launch_bounds__(256, 3) void gemm_kernel(
    const unsigned short* __restrict__ f1n, const unsigned short* __restrict__ f2n,
    float* __restrict__ rowsum, float* __restrict__ rowsumexp,
    float* __restrict__ colsum, float* __restrict__ colsumexp)
{
    __shared__ char As[128 * 128];   // 128 rows x 64 bf16
    __shared__ char Bs[128 * 128];
    const int bid = blockIdx.x;
    const int bm = bid >> 6, bn = bid & 63;
    const int w = threadIdx.x >> 6, lane = threadIdx.x & 63;
    const int wr = (w >> 1) * 64, wc = (w & 1) * 64;   // 2x2 wave grid, 64x64 each
    const int lhi = lane >> 4, llo = lane & 15;

    const char* baseA = (const char*)f1n + (size_t)bm * 128 * 512;
    const char* baseB = (const char*)f2n + (size_t)bn * 128 * 512;

    f32x4 acc[4][4];
#pragma unroll
    for (int m = 0; m < 4; ++m)
#pragma unroll
        for (int n = 0; n < 4; ++n)
            acc[m][n] = (f32x4){0.f, 0.f, 0.f, 0.f};

    for (int kt = 0; kt < 4; ++kt) {
        if (kt > 0) __syncthreads();               // prior reads done before overwrite
        // ---- stage A/B K-slab: each wave 32 rows x 128B per matrix (4 loads) ----
        const char* sA = baseA + kt * 128;
        const char* sB = baseB + kt * 128;
#pragma unroll
        for (int i = 0; i < 4; ++i) {
            const int r = w * 32 + i * 8 + (lane >> 3);     // per-lane source row
            const int cs = (lane & 7) ^ (r & 7);            // pre-swizzled source chunk
            char* dA = As + (w * 32 + i * 8) * 128;         // wave-uniform dest base
            char* dB = Bs + (w * 32 + i * 8) * 128;
            __builtin_amdgcn_global_load_lds(
                (const __attribute__((address_space(1))) unsigned int*)(sA + (size_t)r * 512 + cs * 16),
                (__attribute__((address_space(3))) unsigned int*)dA, 16, 0, 0);
            __builtin_amdgcn_global_load_lds(
                (const __attribute__((address_space(1))) unsigned int*)(sB + (size_t)r * 512 + cs * 16),
                (__attribute__((address_space(3))) unsigned int*)dB, 16, 0, 0);
        }
        __syncthreads();

        // ---- compute: 2 k-slices of 32; 8 ds_read_b128 + 16 MFMA each ----
#pragma unroll
        for (int kk = 0; kk < 2; ++kk) {
            short8 av[4], bv[4];
            const int kb = kk * 64 + lhi * 16;
#pragma unroll
            for (int m = 0; m < 4; ++m) {
                const int ra = wr + m * 16 + llo;
                av[m] = *(const short8*)(As + ra * 128 + (kb ^ ((ra & 7) << 4)));
                const int rb = wc + m * 16 + llo;
                bv[m] = *(const short8*)(Bs + rb * 128 + (kb ^ ((rb & 7) << 4)));
            }
#pragma unroll
            for (int m = 0; m < 4; ++m)
#pragma unroll
                for (int n = 0; n < 4; ++n)
                    acc[m][n] = __builtin_amdgcn_mfma_f32_16x16x32_bf16(av[m], bv[n], acc[m][n], 0, 0, 0);
        }
    }

    // Epilogue: C/D layout col=lane&15, row=(lane>>4)*4+j (validated round 1).
    const int grow = bm * 128 + wr + lhi * 4;
    const int gcol = bn * 128 + wc + llo;
    float cvv[4] = {0.f, 0.f, 0.f, 0.f}, cee[4] = {0.f, 0.f, 0.f, 0.f};
#pragma unroll
    for (int m = 0; m < 4; ++m) {
#pragma unroll
        for (int j = 0; j < 4; ++j) {
            float rv = 0.f, re = 0.f;
#pragma unroll
            for (int n = 0; n < 4; ++n) {
                const float x = acc[m][n][j];
                const float ex = __expf(x);
                rv += x; re += ex;
                cvv[n] += x; cee[n] += ex;
            }
#pragma unroll
            for (int off = 1; off < 16; off <<= 1) {   // reduce across the 16 cols
                rv += __shfl_xor(rv, off);
                re += __shfl_xor(re, off);
            }
            if (llo == 0) {
                const int r = grow + m * 16 + j;
                atomicAdd(&rowsum[r], rv);
                atomicAdd(&rowsumexp[r], re);
            }
        }
    }
#pragma unroll
    for (int n = 0; n < 4; ++n) {                      // reduce across the 16 rows
        float v = cvv[n], e = cee[n];
        v += __shfl_xor(v, 16); e += __shfl_xor(e, 16);
        v += __shfl_xor(v, 32); e += __shfl_xor(e, 32);
        if (lhi == 0) {
            const int c = gcol + n * 16;
            atomicAdd(&colsum[c], v);
            atomicAdd(&colsumexp[c], e);
        }
    }
}

__global__ __launch_bounds__(256) void fin_kernel(
    const float* __restrict__ rowsum, const float* __restrict__ rowsumexp,
    const float* __restrict__ colsum, const float* __restrict__ colsumexp,
    const float* __restrict__ diag, const float* __restrict__ wts,
    float* __restrict__ out)
{
    const float invN = 1.0f / (float)NN;
    float accum = 0.f;
    for (int i = threadIdx.x; i < NN; i += 256) {
        const float eps = 1.f - 0.9f / (1.f + __expf(-5.f * wts[i]));
        const float om = 1.f - eps;
        const float d = diag[i];
        accum += __logf(rowsumexp[i]) - om * d - eps * rowsum[i] * invN;
        accum += __logf(colsumexp[i]) - om * d - eps * colsum[i] * invN;
    }
#pragma unroll
    for (int off = 1; off < 64; off <<= 1) accum += __shfl_xor(accum, off);
    __shared__ float red[4];
    if ((threadIdx.x & 63) == 0) red[threadIdx.x >> 6] = accum;
    __syncthreads();
    if (threadIdx.x == 0)
        out[0] = (red[0] + red[1] + red[2] + red[3]) * (invN * 0.5f);
}

extern "C" void kernel_launch(void* const* d_in, const int* in_sizes, int n_in,
                              void* d_out, int out_size, void* d_ws, size_t ws_size,
                              hipStream_t stream) {
    (void)in_sizes; (void)n_in; (void)out_size; (void)ws_size;
    const float* f1 = (const float*)d_in[0];
    const float* f2 = (const float*)d_in[1];
    const float* scale = (const float*)d_in[2];
    const float* wts = (const float*)d_in[3];
    float* out = (float*)d_out;

    char* ws = (char*)d_ws;
    unsigned short* f1n = (unsigned short*)ws;                              // 4 MB
    unsigned short* f2n = (unsigned short*)(ws + (size_t)4 * 1024 * 1024);  // 4 MB
    float* acc = (float*)(ws + (size_t)8 * 1024 * 1024);
    float* rowsum = acc;
    float* rowsumexp = acc + NN;
    float* colsum = acc + 2 * NN;
    float* colsumexp = acc + 3 * NN;
    float* diag = acc + 4 * NN;

    hipMemsetAsync(acc, 0, (size_t)4 * NN * sizeof(float), stream);
    nrm_kernel<<<NN / 4, 256, 0, stream>>>(f1, f2, scale, f1n, f2n, diag);
    gemm_kernel<<<64 * 64, 256, 0, stream>>>(f1n, f2n, rowsum, rowsumexp, colsum, colsumexp);
    fin_kernel<<<1, 256, 0, stream>>>(rowsum, rowsumexp, colsum, colsumexp, diag, wts, out);
}

// Round 3
// 80.385 us; speedup vs baseline: 2.6693x; 2.2947x over previous
//
#include <hip/hip_runtime.h>
#include <hip/hip_bf16.h>

#define NN 8192
#define DD 256

typedef __attribute__((ext_vector_type(8))) short short8;
typedef __attribute__((ext_vector_type(4))) float f32x4;

__device__ __forceinline__ unsigned short f2bf(float x) {
    unsigned int u = __float_as_uint(x);
    u += 0x7fff + ((u >> 16) & 1);
    return (unsigned short)(u >> 16);
}
__device__ __forceinline__ float bf2f(unsigned short u) {
    return __uint_as_float(((unsigned int)u) << 16);
}

// One wave per row: L2-normalize, fold logit_scale into f1, emit bf16 + fp32 diag.
__global__ __launch_bounds__(256) void nrm_kernel(
    const float* __restrict__ f1, const float* __restrict__ f2,
    const float* __restrict__ scale_p,
    unsigned short* __restrict__ f1n, unsigned short* __restrict__ f2n,
    float* __restrict__ diag)
{
    const int w = threadIdx.x >> 6, lane = threadIdx.x & 63;
    const int row = blockIdx.x * 4 + w;
    const float4 a = reinterpret_cast<const float4*>(f1 + (size_t)row * DD)[lane];
    const float4 b = reinterpret_cast<const float4*>(f2 + (size_t)row * DD)[lane];
    float sa = a.x * a.x + a.y * a.y + a.z * a.z + a.w * a.w;
    float sb = b.x * b.x + b.y * b.y + b.z * b.z + b.w * b.w;
    float sab = a.x * b.x + a.y * b.y + a.z * b.z + a.w * b.w;
#pragma unroll
    for (int off = 1; off < 64; off <<= 1) {
        sa += __shfl_xor(sa, off);
        sb += __shfl_xor(sb, off);
        sab += __shfl_xor(sab, off);
    }
    const float s = scale_p[0];
    const float n1 = fmaxf(sqrtf(sa), 1e-12f);
    const float n2 = fmaxf(sqrtf(sb), 1e-12f);
    if (lane == 0) diag[row] = s * sab / (n1 * n2);
    const float r1 = s / n1, r2 = 1.0f / n2;
    ushort4 o1, o2;
    o1.x = f2bf(a.x * r1); o1.y = f2bf(a.y * r1);
    o1.z = f2bf(a.z * r1); o1.w = f2bf(a.w * r1);
    o2.x = f2bf(b.x * r2); o2.y = f2bf(b.y * r2);
    o2.z = f2bf(b.z * r2); o2.w = f2bf(b.w * r2);
    reinterpret_cast<ushort4*>(f1n + (size_t)row * DD)[lane] = o1;
    reinterpret_cast<ushort4*>(f2n + (size_t)row * DD)[lane] = o2;
}

// S1 = sum_i f1n_i, T1 = sum_i eps_i f1n_i (and same for f2n) -- 256-dim each.
__global__ __launch_bounds__(256) void sumvec_kernel(
    const unsigned short* __restrict__ f1n, const unsigned short* __restrict__ f2n,
    const float* __restrict__ wts,
    float* __restrict__ S1, float* __restrict__ S2,
    float* __restrict__ T1, float* __restrict__ T2)
{
    __shared__ float epsLds[128];
    const int t = threadIdx.x;
    const int row0 = blockIdx.x * 128;
    if (t < 128)
        epsLds[t] = 1.f - 0.9f / (1.f + __expf(-5.f * wts[row0 + t]));
    __syncthreads();
    const int mat = t >> 7;          // 0: f1n, 1: f2n
    const int half = (t >> 6) & 1;   // row half (64 rows each)
    const int cg = t & 63;           // column group of 4
    const unsigned short* src = (mat ? f2n : f1n) + (size_t)(row0 + half * 64) * DD + cg * 4;
    float s0 = 0, s1 = 0, s2 = 0, s3 = 0, w0 = 0, w1 = 0, w2 = 0, w3 = 0;
    for (int i = 0; i < 64; ++i) {
        const ushort4 v = *reinterpret_cast<const ushort4*>(src + (size_t)i * DD);
        const float e = epsLds[half * 64 + i];
        const float a = bf2f(v.x), b = bf2f(v.y), c = bf2f(v.z), d = bf2f(v.w);
        s0 += a; s1 += b; s2 += c; s3 += d;
        w0 += e * a; w1 += e * b; w2 += e * c; w3 += e * d;
    }
    float* S = mat ? S2 : S1;
    float* T = mat ? T2 : T1;
    atomicAdd(&S[cg * 4 + 0], s0); atomicAdd(&S[cg * 4 + 1], s1);
    atomicAdd(&S[cg * 4 + 2], s2); atomicAdd(&S[cg * 4 + 3], s3);
    atomicAdd(&T[cg * 4 + 0], w0); atomicAdd(&T[cg * 4 + 1], w1);
    atomicAdd(&T[cg * 4 + 2], w2); atomicAdd(&T[cg * 4 + 3], w3);
}

// Block = 128 rows x 1024-col chunk. A (full K=256) in registers; B-tiles of
// 64 cols double-buffered in LDS via global_load_lds (XOR-swizzled, rule #21).
// Per-tile epilogue: exp only; row expsums in regs across the walk, col
// expsums via LDS colbuf. Atomics only at block end.
__global__ __launch_bounds__(256, 2) void gemm_kernel(
    const unsigned short* __restrict__ f1n, const unsigned short* __restrict__ f2n,
    float* __restrict__ rowsumexp, float* __restrict__ colsumexp)
{
    __shared__ char Bs[2][64 * 512];
    __shared__ float colbuf[2][1024];
    const int bid = blockIdx.x;
    const int bm = bid >> 3, bc = bid & 7;
    const int w = threadIdx.x >> 6, lane = threadIdx.x & 63;
    const int wr = (w >> 1) * 64, wc = (w & 1) * 32;   // waves: 2 row-halves x 2 col-halves
    const int lhi = lane >> 4, llo = lane & 15;

    // ---- A fragments: this wave's 64 rows, full K, in registers (128 VGPR) ----
    const char* aBase = (const char*)f1n + ((size_t)(bm * 128 + wr + llo) * 512) + lhi * 16;
    short8 av[4][8];
#pragma unroll
    for (int m = 0; m < 4; ++m)
#pragma unroll
        for (int ks = 0; ks < 8; ++ks)
            av[m][ks] = *(const short8*)(aBase + (size_t)(m * 16) * 512 + ks * 64);

    const char* bBase = (const char*)f2n + (size_t)bc * 1024 * 512;

    auto stage = [&](int buf, int tile) {
#pragma unroll
        for (int i = 0; i < 8; ++i) {
            const int r = w * 16 + i * 2 + (lane >> 5);      // per-lane source row
            const int cs = (lane & 31) ^ (r & 7);            // pre-swizzled source chunk
            __builtin_amdgcn_global_load_lds(
                (const __attribute__((address_space(1))) unsigned int*)
                    (bBase + (size_t)(tile * 64 + r) * 512 + cs * 16),
                (__attribute__((address_space(3))) unsigned int*)
                    (&Bs[buf][(w * 16 + i * 2) * 512]), 16, 0, 0);
        }
    };

    float rowpart[16];
#pragma unroll
    for (int i = 0; i < 16; ++i) rowpart[i] = 0.f;

    stage(0, 0);
    __syncthreads();

    for (int t = 0; t < 16; ++t) {
        const int cur = t & 1;
        if (t < 15) stage(cur ^ 1, t + 1);   // issue next-tile loads BEFORE compute

        f32x4 acc[4][2];
#pragma unroll
        for (int m = 0; m < 4; ++m) {
            acc[m][0] = (f32x4){0.f, 0.f, 0.f, 0.f};
            acc[m][1] = (f32x4){0.f, 0.f, 0.f, 0.f};
        }
        const char* bs = Bs[cur];
#pragma unroll
        for (int ks = 0; ks < 8; ++ks) {
            const int kb = ks * 64 + lhi * 16;
            const int rb0 = wc + llo, rb1 = wc + 16 + llo;
            const short8 bv0 = *(const short8*)(bs + rb0 * 512 + (kb ^ ((rb0 & 7) << 4)));
            const short8 bv1 = *(const short8*)(bs + rb1 * 512 + (kb ^ ((rb1 & 7) << 4)));
#pragma unroll
            for (int m = 0; m < 4; ++m) {
                acc[m][0] = __builtin_amdgcn_mfma_f32_16x16x32_bf16(av[m][ks], bv0, acc[m][0], 0, 0, 0);
                acc[m][1] = __builtin_amdgcn_mfma_f32_16x16x32_bf16(av[m][ks], bv1, acc[m][1], 0, 0, 0);
            }
        }

        // per-tile epilogue: exp + accumulate (no VMEM ops in the loop)
        float cee0 = 0.f, cee1 = 0.f;
#pragma unroll
        for (int m = 0; m < 4; ++m)
#pragma unroll
            for (int j = 0; j < 4; ++j) {
                const float e0 = __expf(acc[m][0][j]);
                const float e1 = __expf(acc[m][1][j]);
                rowpart[m * 4 + j] += e0 + e1;
                cee0 += e0; cee1 += e1;
            }
        cee0 += __shfl_xor(cee0, 16); cee0 += __shfl_xor(cee0, 32);
        cee1 += __shfl_xor(cee1, 16); cee1 += __shfl_xor(cee1, 32);
        if (lhi == 0) {
            colbuf[w >> 1][t * 64 + wc + llo] = cee0;
            colbuf[w >> 1][t * 64 + wc + 16 + llo] = cee1;
        }
        __syncthreads();   // drains stage vmcnt + colbuf writes; next tile ready
    }

    // block-end: row expsums (reduce over 16 llo lanes; row = wr+m*16+lhi*4+j)
#pragma unroll
    for (int m = 0; m < 4; ++m)
#pragma unroll
        for (int j = 0; j < 4; ++j) {
            float v = rowpart[m * 4 + j];
            v += __shfl_xor(v, 1); v += __shfl_xor(v, 2);
            v += __shfl_xor(v, 4); v += __shfl_xor(v, 8);
            if (llo == 0)
                atomicAdd(&rowsumexp[bm * 128 + wr + m * 16 + lhi * 4 + j], v);
        }
    // block-end: col expsums (combine the two row-half parts)
    for (int c = threadIdx.x; c < 1024; c += 256)
        atomicAdd(&colsumexp[bc * 1024 + c], colbuf[0][c] + colbuf[1][c]);
}

// 32 blocks x 256 threads: one row per thread -> per-block partial into totalp.
__global__ __launch_bounds__(256) void finA_kernel(
    const float* __restrict__ rse, const float* __restrict__ cse,
    const float* __restrict__ diag, const float* __restrict__ wts,
    float* __restrict__ totalp)
{
    const int i = blockIdx.x * 256 + threadIdx.x;
    const float eps = 1.f - 0.9f / (1.f + __expf(-5.f * wts[i]));
    float a = __logf(rse[i]) + __logf(cse[i]) - 2.f * (1.f - eps) * diag[i];
#pragma unroll
    for (int off = 1; off < 64; off <<= 1) a += __shfl_xor(a, off);
    __shared__ float red[4];
    if ((threadIdx.x & 63) == 0) red[threadIdx.x >> 6] = a;
    __syncthreads();
    if (threadIdx.x == 0)
        atomicAdd(totalp, red[0] + red[1] + red[2] + red[3]);
}

__global__ __launch_bounds__(256) void finB_kernel(
    const float* __restrict__ S1, const float* __restrict__ S2,
    const float* __restrict__ T1, const float* __restrict__ T2,
    const float* __restrict__ totalp, float* __restrict__ out)
{
    const int t = threadIdx.x;
    float d = T1[t] * S2[t] + S1[t] * T2[t];
#pragma unroll
    for (int off = 1; off < 64; off <<= 1) d += __shfl_xor(d, off);
    __shared__ float red[4];
    if ((t & 63) == 0) red[t >> 6] = d;
    __syncthreads();
    if (t == 0) {
        const float dot = red[0] + red[1] + red[2] + red[3];
        out[0] = (totalp[0] - dot * (1.f / (float)NN)) * (1.f / (2.f * (float)NN));
    }
}

extern "C" void kernel_launch(void* const* d_in, const int* in_sizes, int n_in,
                              void* d_out, int out_size, void* d_ws, size_t ws_size,
                              hipStream_t stream) {
    (void)in_sizes; (void)n_in; (void)out_size; (void)ws_size;
    const float* f1 = (const float*)d_in[0];
    const float* f2 = (const float*)d_in[1];
    const float* scale = (const float*)d_in[2];
    const float* wts = (const float*)d_in[3];
    float* out = (float*)d_out;

    char* ws = (char*)d_ws;
    unsigned short* f1n = (unsigned short*)ws;                              // 4 MB
    unsigned short* f2n = (unsigned short*)(ws + (size_t)4 * 1024 * 1024);  // 4 MB
    float* fb = (float*)(ws + (size_t)8 * 1024 * 1024);
    float* rse = fb;                 // 8192
    float* cse = fb + 8192;          // 8192
    float* S1 = fb + 16384;          // 256
    float* S2 = fb + 16640;
    float* T1 = fb + 16896;
    float* T2 = fb + 17152;
    float* totalp = fb + 17408;      // 1 (+pad)
    float* diag = fb + 18432;        // 8192 (not zeroed)

    hipMemsetAsync(fb, 0, (size_t)18432 * sizeof(float), stream);
    nrm_kernel<<<NN / 4, 256, 0, stream>>>(f1, f2, scale, f1n, f2n, diag);
    sumvec_kernel<<<64, 256, 0, stream>>>(f1n, f2n, wts, S1, S2, T1, T2);
    gemm_kernel<<<512, 256, 0, stream>>>(f1n, f2n, rse, cse);
    finA_kernel<<<32, 256, 0, stream>>>(rse, cse, diag, wts, totalp);
    finB_kernel<<<1, 256, 0, stream>>>(S1, S2, T1, T2, totalp, out);
}